// Round 5
// baseline (25591.533 us; speedup 1.0000x reference)
//
#include <hip/hip_runtime.h>
#include <math.h>

// Problem constants
#define B 64
#define T 512
#define F 256
#define U 1024
#define NBLK 256
#define NTH 512
#define WPAD 68   // zbuf row stride (floats): 68%32=4 -> conflict-free b128 partial stores

typedef unsigned short ushort_t;
typedef __attribute__((ext_vector_type(8))) _Float16 f16x8_t;  // MFMA A/B frag (4 VGPR)
typedef __attribute__((ext_vector_type(4))) float f32x4_t;     // MFMA C/D frag

// ---------------- workspace layout (BYTE offsets) ----------------
static const size_t OFF_STATS= 0;                  // fp32 [2 parity][64 b][8]: 4096
static const size_t OFF_COND = 4096;               // int[512]: 2048
static const size_t OFF_BAR  = 6144;               // int[320]: 1280
static const size_t OFF_H2B  = 7424;               // fp32 [256 ublk][64 b][4]: 262144
static const size_t OFF_HS   = 269568;             // f16 [2][3][256 ublk][64 b][4]: 786432
static const size_t OFF_YB   = 1056000;            // f16 y [64 fblk][64 b][4]: 32768 (old xs slot)
static const size_t OFF_PW0  = 1088768;            // f16 [256 g][40 kt][512]: 10485760
static const size_t OFF_PW1  = 11574528;           // f16 [256][64][512]: 16777216
static const size_t OFF_PW2  = 28351744;           // f16 [256][64][512]: 16777216
static const size_t ZERO_BYTES = OFF_PW0;          // state region zeroed each launch
// bar int-offsets: sub[i]=i*16 (i<8, monotonic, never reset); master=128;
// relay[i]=144+i*16.

__device__ __forceinline__ float sigm(float x) {
    return 1.0f / (1.0f + __expf(-x));
}

__device__ __forceinline__ ushort_t f2h(float x) {   // RNE fp32->fp16
    _Float16 h = (_Float16)x;
    union { _Float16 h; ushort_t u; } v; v.h = h;
    return v.u;
}
__device__ __forceinline__ float h2f(ushort_t u) {
    union { ushort_t u; _Float16 h; } v; v.u = u;
    return (float)v.h;
}

// ---- write-through (device-coherent) stores: data lands at the coherence
// point; consumers use PLAIN loads + the once-per-step acquire inv.
__device__ __forceinline__ void store_uc_u16(ushort_t* p, ushort_t v) {
    asm volatile("global_store_short %0, %1, off sc0 sc1"
                 :: "v"(p), "v"((unsigned)v) : "memory");
}
__device__ __forceinline__ void store_uc_f32(float* p, float v) {
    asm volatile("global_store_dword %0, %1, off sc0 sc1"
                 :: "v"(p), "v"(v) : "memory");
}
__device__ __forceinline__ void store_uc_b64(void* p, unsigned long long v) {
    asm volatile("global_store_dwordx2 %0, %1, off sc0 sc1"
                 :: "v"(p), "v"(v) : "memory");
}
__device__ __forceinline__ void drain_vmem() {
    asm volatile("s_waitcnt vmcnt(0)" ::: "memory");
}

// Hierarchical MONOTONIC barrier (R4) minus the frequent insurance acquire:
// relaxed agent-scope atomic loads already bypass L1/L2 and read the
// coherence point, so polls are always fresh; the old every-64-spin ACQUIRE
// load emitted an L2 invalidate that nuked co-resident blocks' cached state
// mid-phase. Keep a rare (256-spin) backstop only.
__device__ __forceinline__ void phase_sync(int* bar, int epoch, int g) {
    drain_vmem();        // own write-through stores reach coherence point
    __syncthreads();
    if (threadIdx.x == 0) {
        const int sub = g & 7;
        const int prev = __hip_atomic_fetch_add(bar + sub * 16, 1,
                                                __ATOMIC_RELAXED, __HIP_MEMORY_SCOPE_AGENT);
        if (prev == epoch * 32 - 1) {
            const int pm = __hip_atomic_fetch_add(bar + 128, 1,
                                                  __ATOMIC_RELAXED, __HIP_MEMORY_SCOPE_AGENT);
            if (pm == epoch * 8 - 1) {
                #pragma unroll
                for (int i = 0; i < 8; ++i)
                    __hip_atomic_store(bar + 144 + i * 16, epoch, __ATOMIC_RELAXED,
                                       __HIP_MEMORY_SCOPE_AGENT);
            }
        }
        int* myrelay = bar + 144 + sub * 16;
        int spins = 0;
        while (__hip_atomic_load(myrelay, __ATOMIC_RELAXED,
                                 __HIP_MEMORY_SCOPE_AGENT) < epoch) {
            __builtin_amdgcn_s_sleep(1);
            if ((++spins & 255) == 0)
                (void)__hip_atomic_load(myrelay, __ATOMIC_ACQUIRE,
                                        __HIP_MEMORY_SCOPE_AGENT);
        }
    }
    __syncthreads();
}

// Prep: decode conditioned_lst (bool-u8 vs int32 sniff). (xs seeding gone:
// step 0 reads input directly in the fused P0 x-construct.)
__global__ void prep_kernel(const unsigned char* __restrict__ condraw,
                            unsigned char* __restrict__ wsb) {
    __shared__ int s_not_int32;
    const int tid = threadIdx.x;
    if (tid == 0) s_not_int32 = 0;
    __syncthreads();
    if (tid < 512 && (tid & 3) != 0) {
        if (condraw[tid] != 0) s_not_int32 = 1;
    }
    __syncthreads();
    const int is32 = (s_not_int32 == 0);
    int* condw = (int*)(wsb + OFF_COND);
    if (tid < 512) {
        int cv = is32 ? ((const int*)condraw)[tid] : (int)condraw[tid];
        condw[tid] = (cv != 0) ? 1 : 0;
    }
}

// Repack fp32 weights -> fp16 in MFMA B-fragment order (unchanged).
__global__ void repack_kernel(const float* __restrict__ W0,
                              const float* __restrict__ W1,
                              const float* __restrict__ W2,
                              unsigned char* __restrict__ wsb) {
    ushort_t* P0 = (ushort_t*)(wsb + OFF_PW0);
    ushort_t* P1 = (ushort_t*)(wsb + OFF_PW1);
    ushort_t* P2 = (ushort_t*)(wsb + OFF_PW2);
    const size_t stride = (size_t)gridDim.x * blockDim.x;
    const size_t tid = (size_t)blockIdx.x * blockDim.x + threadIdx.x;
    const size_t N0 = (size_t)256 * 40 * 512;
    const size_t N12 = (size_t)256 * 64 * 512;
    for (size_t i = tid; i < N0; i += stride) {
        const int g = (int)(i / 20480);
        const int r = (int)(i % 20480);
        const int kt = r >> 9, s = r & 511, L = s >> 3, j = s & 7;
        const int k = kt * 32 + ((L >> 4) << 3) + j;
        const int n = L & 15;
        const int col = ((n >> 2) << 10) + (g << 2) + (n & 3);
        P0[i] = f2h(W0[(size_t)k * 4096 + col]);
    }
    for (size_t i = tid; i < N12; i += stride) {
        const int g = (int)(i / 32768);
        const int r = (int)(i % 32768);
        const int kt = r >> 9, s = r & 511, L = s >> 3, j = s & 7;
        const int k = kt * 32 + ((L >> 4) << 3) + j;
        const int n = L & 15;
        const int col = ((n >> 2) << 10) + (g << 2) + (n & 3);
        const size_t src = (size_t)k * 4096 + col;
        P1[i] = f2h(W1[src]);
        P2[i] = f2h(W2[src]);
    }
}

__global__ void __launch_bounds__(NTH, 2)
lstm_persistent(const float* __restrict__ input,
                const float* __restrict__ b0, const float* __restrict__ b1,
                const float* __restrict__ b2,
                const float* __restrict__ Wd, const float* __restrict__ bd,
                const float* __restrict__ gamma, const float* __restrict__ beta,
                float* __restrict__ out, unsigned char* __restrict__ wsb) {
    const int g = blockIdx.x;
    const int tid = threadIdx.x;
    const int lane = tid & 63;
    const int wv = __builtin_amdgcn_readfirstlane(tid >> 6);  // 0..7
    const int ln15 = lane & 15;
    const int quad = lane >> 4;

    float* h2b = (float*)(wsb + OFF_H2B);          // fp32 [256 ublk][64 b][4]
    float* stats = (float*)(wsb + OFF_STATS);      // fp32 [2][64][8]
    int* bar = (int*)(wsb + OFF_BAR);
    ushort_t* hs = (ushort_t*)(wsb + OFF_HS);      // f16 [2][3][256][64][4]
    ushort_t* yb = (ushort_t*)(wsb + OFF_YB);      // f16 y [64 fblk][64 b][4]
    const size_t HSZ = (size_t)256 * 64 * 4;       // ushorts per [parity][layer] tile

    __shared__ f16x8_t lds_pw0[40 * 64];     // 40 KB: L0 B-frags
    __shared__ f32x4_t lds_wd4[1024];        // 16 KB: Wd cols (g<64)
    __shared__ float zbuf[128 * WPAD];       // 34.8 KB
    __shared__ float zbuf2[128];             // per-batch (mu, rs)
    __shared__ int lds_cond[512];            // 2 KB

    const int u0 = g << 2;
    const int f0 = g << 2;
    const int k0 = (wv << 5) + (quad << 3);  // this lane's x-feature base
    const int fb0 = k0 >> 2;

    // B-frags in regs: Bw[0..3] = x-part kts (4wv+c); Bw[4..7] = h-part
    // kts (32+4wv+c).
    f16x8_t Bw1[8], Bw2[8];
    {
        const ushort_t* p1 = (const ushort_t*)(wsb + OFF_PW1) +
                             (size_t)g * 64 * 512 + (size_t)lane * 8;
        const ushort_t* p2 = (const ushort_t*)(wsb + OFF_PW2) +
                             (size_t)g * 64 * 512 + (size_t)lane * 8;
        #pragma unroll
        for (int i = 0; i < 4; ++i) {
            Bw1[i]     = *(const f16x8_t*)(p1 + (size_t)((wv << 2) + i) * 512);
            Bw1[4 + i] = *(const f16x8_t*)(p1 + (size_t)(32 + (wv << 2) + i) * 512);
            Bw2[i]     = *(const f16x8_t*)(p2 + (size_t)((wv << 2) + i) * 512);
            Bw2[4 + i] = *(const f16x8_t*)(p2 + (size_t)(32 + (wv << 2) + i) * 512);
        }
    }
    {
        const f16x8_t* src = (const f16x8_t*)((const ushort_t*)(wsb + OFF_PW0) +
                                              (size_t)g * 40 * 512);
        for (int i = tid; i < 40 * 64; i += NTH) lds_pw0[i] = src[i];
    }
    if (g < 64) {
        for (int k = tid; k < 1024; k += NTH)
            lds_wd4[k] = *(const f32x4_t*)(Wd + (size_t)k * F + f0);
    }
    for (int i = tid; i < 512; i += NTH) lds_cond[i] = ((const int*)(wsb + OFF_COND))[i];

    // NEW gate-thread map: eb=tid>>2, eu=tid&3 -> gate store address is
    // base + g*256 + tid (perfectly contiguous full-line wave stores; the
    // old eb=tid&63/eu=tid>>6 map write-throughed 2B-per-8B partial lines,
    // 4x HBM write amplification + slow drains).
    const int eb = tid >> 2;
    const int eu = tid & 3;

    float bias0[4], bias1[4], bias2[4];
    if (tid < 256) {
        #pragma unroll
        for (int q = 0; q < 4; ++q) {
            bias0[q] = b0[(q << 10) + u0 + eu];
            bias1[q] = b1[(q << 10) + u0 + eu];
            bias2[q] = b2[(q << 10) + u0 + eu];
        }
    }
    // per-lane LN params for this lane's 8 x-features (survive inv in regs)
    float gmv[8], btv[8];
    {
        const float4 g0 = *(const float4*)(gamma + k0);
        const float4 g1 = *(const float4*)(gamma + k0 + 4);
        const float4 t0 = *(const float4*)(beta + k0);
        const float4 t1 = *(const float4*)(beta + k0 + 4);
        gmv[0]=g0.x; gmv[1]=g0.y; gmv[2]=g0.z; gmv[3]=g0.w;
        gmv[4]=g1.x; gmv[5]=g1.y; gmv[6]=g1.z; gmv[7]=g1.w;
        btv[0]=t0.x; btv[1]=t0.y; btv[2]=t0.z; btv[3]=t0.w;
        btv[4]=t1.x; btv[5]=t1.y; btv[6]=t1.z; btv[7]=t1.w;
    }
    float4 gm4 = {0,0,0,0}, bt4 = {0,0,0,0}, bd4 = {0,0,0,0};
    if (g < 64 && wv == 1) {       // out-writer wave's f-slice LN params
        gm4 = *(const float4*)(gamma + f0);
        bt4 = *(const float4*)(beta + f0);
    }
    if (g < 64 && wv == 0) {
        bd4 = *(const float4*)(bd + f0);
    }
    __syncthreads();

    float creg0 = 0.f, creg1 = 0.f, creg2 = 0.f;

    f32x4_t acc0[4], acc1[4], acc2[4];
    #pragma unroll
    for (int mt = 0; mt < 4; ++mt) {
        acc0[mt] = (f32x4_t){0.f, 0.f, 0.f, 0.f};
        acc1[mt] = (f32x4_t){0.f, 0.f, 0.f, 0.f};
        acc2[mt] = (f32x4_t){0.f, 0.f, 0.f, 0.f};
    }

    // plain-load A-fragment: two 8B chunks 512B apart (blocked layout)
    auto ld_frag = [&](const char* p) -> f16x8_t {
        union { unsigned long long q[2]; f16x8_t v; } u;
        u.q[0] = *(const unsigned long long*)(p);
        u.q[1] = *(const unsigned long long*)(p + 512);
        return u.v;
    };

    auto mm4 = [&](f32x4_t (&acc)[4], const ushort_t* base,
                   const f16x8_t (&Bw)[8], const int boff) {
        f16x8_t Ab[4][4];
        const char* bb = (const char*)base + (size_t)ln15 * 8 +
                         (size_t)(quad << 1) * 512;
        #pragma unroll
        for (int c = 0; c < 4; ++c) {
            const char* pc = bb + (size_t)((wv << 2) + c) * 4096;
            #pragma unroll
            for (int mt = 0; mt < 4; ++mt)
                Ab[c][mt] = ld_frag(pc + mt * 128);
        }
        #pragma unroll
        for (int c = 0; c < 4; ++c) {
            #pragma unroll
            for (int mt = 0; mt < 4; ++mt)
                acc[mt] = __builtin_amdgcn_mfma_f32_16x16x32_f16(
                    Ab[c][mt], Bw[boff + c], acc[mt], 0, 0, 0);
        }
    };

    // L0 h-part: kts 8+4wv+c. B-frag index uses kt (8+4wv+c); A-data column
    // is k - F = (4wv+c)*32 -> A ublk base (4wv+c)*4096.
    auto mm_h0 = [&](f32x4_t (&acc)[4], const ushort_t* base) {
        f16x8_t Ab[4][4];
        const char* bb = (const char*)base + (size_t)ln15 * 8 +
                         (size_t)(quad << 1) * 512;
        #pragma unroll
        for (int c = 0; c < 4; ++c) {
            const char* pc = bb + (size_t)((wv << 2) + c) * 4096;
            #pragma unroll
            for (int mt = 0; mt < 4; ++mt)
                Ab[c][mt] = ld_frag(pc + mt * 128);
        }
        #pragma unroll
        for (int c = 0; c < 4; ++c) {
            const f16x8_t Bb = lds_pw0[(8 + (wv << 2) + c) * 64 + lane];
            #pragma unroll
            for (int mt = 0; mt < 4; ++mt)
                acc[mt] = __builtin_amdgcn_mfma_f32_16x16x32_f16(
                    Ab[c][mt], Bb, acc[mt], 0, 0, 0);
        }
    };

    // dump acc -> zbuf, zero acc, 8-wave reduce + gates + contiguous h store.
    auto epilogue = [&](f32x4_t (&acc)[4], const float (&bi)[4], float& cr,
                        ushort_t* hdst, float* h2dst) {
        __syncthreads();
        {
            float* zrow = zbuf + (size_t)(wv * 16 + ln15) * WPAD;
            #pragma unroll
            for (int mt = 0; mt < 4; ++mt)
                *(f32x4_t*)(zrow + mt * 16 + (quad << 2)) = acc[mt];
            #pragma unroll
            for (int mt = 0; mt < 4; ++mt) acc[mt] = (f32x4_t){0.f, 0.f, 0.f, 0.f};
        }
        __syncthreads();
        if (tid < 256) {   // gate epilogue: (b=eb, unit u0+eu)
            float z[4];
            #pragma unroll
            for (int q = 0; q < 4; ++q) {
                float s = bi[q];
                #pragma unroll
                for (int w = 0; w < 8; ++w)
                    s += zbuf[(size_t)(w * 16 + q * 4 + eu) * WPAD + eb];
                z[q] = s;
            }
            const float ig = sigm(z[0]);
            const float gg = tanhf(z[1]);
            const float fg = sigm(z[2] + 1.0f);   // forget_bias = 1.0
            const float og = sigm(z[3]);
            const float cn = cr * fg + ig * gg;
            const float hn = og * tanhf(cn);
            cr = cn;
            // (eb,eu)->(tid>>2,tid&3): addr = base + g*256 + tid, contiguous.
            store_uc_u16(hdst + (size_t)g * 256 + tid, f2h(hn));
            if (h2dst) store_uc_f32(h2dst + (size_t)g * 256 + tid, hn);
        }
    };

    int epoch = 0;
    for (int t = 0; t < T; ++t) {
        const int p = t & 1;
        const int pn = p ^ 1;
        ushort_t* hs0n = hs + (size_t)(pn * 3 + 0) * HSZ;
        ushort_t* hs1n = hs + (size_t)(pn * 3 + 1) * HSZ;
        ushort_t* hs2n = hs + (size_t)(pn * 3 + 2) * HSZ;

        // THE one inv per step.
        __builtin_amdgcn_fence(__ATOMIC_ACQUIRE, "agent");

        // ---- phase 0: dense h-prefetch + stats + redundant emit + L0 x ----
        if (g < 64) {
            mm4(acc1, hs + (size_t)(p * 3 + 1) * HSZ, Bw1, 4);
            mm4(acc2, hs + (size_t)(p * 3 + 2) * HSZ, Bw2, 4);
        }
        // stats of step t-1 (parity pn, summed at L3 by t-1's P3 atomics)
        if (tid < 64) {
            const float2 sv = *(const float2*)(stats + (size_t)pn * (64 * 8) + tid * 8);
            const float mu = sv.x * (1.0f / F);
            const float var = sv.y * (1.0f / F) - mu * mu;
            zbuf2[tid * 2] = mu;
            zbuf2[tid * 2 + 1] = rsqrtf(var + 1e-12f);
        }
        __syncthreads();
        // out-writer: dense wv1 emits step t-1's output for f-slice g
        if (g < 64 && wv == 1 && t > 0) {
            union { unsigned long long q; ushort_t s[4]; } yq;
            yq.q = *(const unsigned long long*)(yb + ((size_t)g * 64 + lane) * 4);
            const float mu = zbuf2[lane * 2], rs = zbuf2[lane * 2 + 1];
            float4 o;
            o.x = fmaxf((h2f(yq.s[0]) - mu) * rs * gm4.x + bt4.x, 0.0f);
            o.y = fmaxf((h2f(yq.s[1]) - mu) * rs * gm4.y + bt4.y, 0.0f);
            o.z = fmaxf((h2f(yq.s[2]) - mu) * rs * gm4.z + bt4.z, 0.0f);
            o.w = fmaxf((h2f(yq.s[3]) - mu) * rs * gm4.w + bt4.w, 0.0f);
            *(float4*)(out + (size_t)lane * (T * F) + (size_t)(t - 1) * F + f0) = o;
        }
        // x-construct (redundant per block -> no producer/consumer sync):
        // x = (t==0 || cond) ? input[:,t,:] : relu(LN(y_{t-1}))
        {
            const int condt = (t == 0) || (lds_cond[t] != 0);
            f16x8_t Ax[4];
            #pragma unroll
            for (int mt = 0; mt < 4; ++mt) {
                const int b = ln15 + (mt << 4);
                union { ushort_t s[8]; f16x8_t v; } ux;
                if (condt) {
                    const float* ip = input + (size_t)b * (T * F) + (size_t)t * F + k0;
                    const float4 a0 = *(const float4*)(ip);
                    const float4 a1 = *(const float4*)(ip + 4);
                    ux.s[0] = f2h(a0.x); ux.s[1] = f2h(a0.y);
                    ux.s[2] = f2h(a0.z); ux.s[3] = f2h(a0.w);
                    ux.s[4] = f2h(a1.x); ux.s[5] = f2h(a1.y);
                    ux.s[6] = f2h(a1.z); ux.s[7] = f2h(a1.w);
                } else {
                    union { unsigned long long q; ushort_t s[4]; } y0, y1;
                    y0.q = *(const unsigned long long*)(yb + ((size_t)fb0 * 64 + b) * 4);
                    y1.q = *(const unsigned long long*)(yb + ((size_t)(fb0 + 1) * 64 + b) * 4);
                    const float mu = zbuf2[b * 2], rs = zbuf2[b * 2 + 1];
                    #pragma unroll
                    for (int j = 0; j < 4; ++j) {
                        ux.s[j] = f2h(fmaxf((h2f(y0.s[j]) - mu) * rs * gmv[j] + btv[j], 0.0f));
                        ux.s[4 + j] = f2h(fmaxf((h2f(y1.s[j]) - mu) * rs * gmv[4 + j] + btv[4 + j], 0.0f));
                    }
                }
                Ax[mt] = ux.v;
            }
            const f16x8_t Bb = lds_pw0[wv * 64 + lane];
            #pragma unroll
            for (int mt = 0; mt < 4; ++mt)
                acc0[mt] = __builtin_amdgcn_mfma_f32_16x16x32_f16(
                    Ax[mt], Bb, acc0[mt], 0, 0, 0);
        }
        epilogue(acc0, bias0, creg0, hs0n, nullptr);
        phase_sync(bar, ++epoch, g);

        // ---- phase 1: L1 x-half (A = h0_t) + dense blocks' L0 h-pf ----
        mm4(acc1, hs0n, Bw1, 0);
        if (g < 64) mm_h0(acc0, hs0n);
        epilogue(acc1, bias1, creg1, hs1n, nullptr);
        phase_sync(bar, ++epoch, g);

        // ---- phase 2: L2 x-half (A = h1_t) ----
        mm4(acc2, hs1n, Bw2, 0);
        epilogue(acc2, bias2, creg2, hs2n, h2b);
        phase_sync(bar, ++epoch, g);

        // ------- phase 3: dense y + stats publish (g<64) / h-pf (g>=64) -------
        if (g < 64) {
            float accd[4] = {0.f, 0.f, 0.f, 0.f};
            #pragma unroll
            for (int half = 0; half < 2; ++half) {
                f32x4_t hv[16];
                const f32x4_t* hb4 = (const f32x4_t*)h2b +
                    (size_t)(wv * 32 + half * 16) * 64 + lane;
                #pragma unroll
                for (int i = 0; i < 16; ++i)
                    hv[i] = hb4[(size_t)i * 64];
                #pragma unroll
                for (int i = 0; i < 16; ++i) {
                    const int k = (wv << 7) + (half << 6) + (i << 2);
                    #pragma unroll
                    for (int j = 0; j < 4; ++j) {
                        const f32x4_t w4 = lds_wd4[k + j];
                        accd[0] = fmaf(w4[0], hv[i][j], accd[0]);
                        accd[1] = fmaf(w4[1], hv[i][j], accd[1]);
                        accd[2] = fmaf(w4[2], hv[i][j], accd[2]);
                        accd[3] = fmaf(w4[3], hv[i][j], accd[3]);
                    }
                }
            }
            __syncthreads();
            #pragma unroll
            for (int jj = 0; jj < 4; ++jj)
                zbuf[(size_t)(wv * 16 + jj) * WPAD + lane] = accd[jj];
            __syncthreads();
            if (wv == 0) {
                float yv[4];
                float s = 0.f, ss = 0.f;
                #pragma unroll
                for (int jj = 0; jj < 4; ++jj) {
                    float y = 0.f;
                    #pragma unroll
                    for (int w = 0; w < 8; ++w)
                        y += zbuf[(size_t)(w * 16 + jj) * WPAD + lane];
                    y += (jj == 0) ? bd4.x : (jj == 1) ? bd4.y : (jj == 2) ? bd4.z : bd4.w;
                    yv[jj] = y;
                    s += y;
                    ss += y * y;
                }
                // publish y slice (f16, contiguous 512B) + stats partials
                unsigned long long pk =
                    (unsigned long long)f2h(yv[0]) |
                    ((unsigned long long)f2h(yv[1]) << 16) |
                    ((unsigned long long)f2h(yv[2]) << 32) |
                    ((unsigned long long)f2h(yv[3]) << 48);
                store_uc_b64(yb + ((size_t)g * 64 + lane) * 4, pk);
                float* st = stats + (size_t)p * (64 * 8);
                atomicAdd(&st[(size_t)lane * 8], s);
                atomicAdd(&st[(size_t)lane * 8 + 1], ss);
                // consumed only after the P3-end grid sync (next P0) -> no minibar
            }
        } else if (g == 64 && wv == 0) {
            // zero other-parity stats for step t+1's P3 accumulation
            float* st2 = stats + (size_t)pn * (64 * 8);
            store_uc_b64(&st2[(size_t)lane * 8], 0ULL);
        }

        if (g >= 64 && t + 1 < T) {
            mm_h0(acc0, hs0n);
            mm4(acc1, hs1n, Bw1, 4);
            mm4(acc2, hs2n, Bw2, 4);
        }
        phase_sync(bar, ++epoch, g);
    }

    // post-loop: emit step T-1's output (dense blocks only; block-local)
    if (g < 64) {
        __builtin_amdgcn_fence(__ATOMIC_ACQUIRE, "agent");
        if (tid < 64) {
            const float2 sv = *(const float2*)(stats + (size_t)((T - 1) & 1) * (64 * 8) + tid * 8);
            const float mu = sv.x * (1.0f / F);
            const float var = sv.y * (1.0f / F) - mu * mu;
            zbuf2[tid * 2] = mu;
            zbuf2[tid * 2 + 1] = rsqrtf(var + 1e-12f);
        }
        __syncthreads();
        if (wv == 1) {
            union { unsigned long long q; ushort_t s[4]; } yq;
            yq.q = *(const unsigned long long*)(yb + ((size_t)g * 64 + lane) * 4);
            const float mu = zbuf2[lane * 2], rs = zbuf2[lane * 2 + 1];
            float4 o;
            o.x = fmaxf((h2f(yq.s[0]) - mu) * rs * gm4.x + bt4.x, 0.0f);
            o.y = fmaxf((h2f(yq.s[1]) - mu) * rs * gm4.y + bt4.y, 0.0f);
            o.z = fmaxf((h2f(yq.s[2]) - mu) * rs * gm4.z + bt4.z, 0.0f);
            o.w = fmaxf((h2f(yq.s[3]) - mu) * rs * gm4.w + bt4.w, 0.0f);
            *(float4*)(out + (size_t)lane * (T * F) + (size_t)(T - 1) * F + f0) = o;
        }
    }
}

extern "C" void kernel_launch(void* const* d_in, const int* in_sizes, int n_in,
                              void* d_out, int out_size, void* d_ws, size_t ws_size,
                              hipStream_t stream) {
    const float* input = (const float*)d_in[0];
    const unsigned char* condraw = (const unsigned char*)d_in[1];
    const float* W0 = (const float*)d_in[2];
    const float* b0 = (const float*)d_in[3];
    const float* W1 = (const float*)d_in[4];
    const float* b1 = (const float*)d_in[5];
    const float* W2 = (const float*)d_in[6];
    const float* b2 = (const float*)d_in[7];
    const float* Wd = (const float*)d_in[8];
    const float* bd = (const float*)d_in[9];
    const float* gamma = (const float*)d_in[10];
    const float* beta = (const float*)d_in[11];
    float* out = (float*)d_out;
    unsigned char* wsb = (unsigned char*)d_ws;

    hipMemsetAsync(d_ws, 0, ZERO_BYTES, stream);
    prep_kernel<<<1, 512, 0, stream>>>(condraw, wsb);
    repack_kernel<<<2048, 256, 0, stream>>>(W0, W1, W2, wsb);
    lstm_persistent<<<NBLK, NTH, 0, stream>>>(input, b0, b1, b2, Wd, bd,
                                              gamma, beta, out, wsb);
}

// Round 6
// 24121.132 us; speedup vs baseline: 1.0610x; 1.0610x over previous
//
#include <hip/hip_runtime.h>
#include <math.h>

// Problem constants
#define B 64
#define T 512
#define F 256
#define U 1024
#define NBLK 256
#define NTH 512
#define WPAD 68   // zbuf row stride (floats)

typedef unsigned short ushort_t;
typedef __attribute__((ext_vector_type(8))) _Float16 f16x8_t;  // MFMA A/B frag (4 VGPR)
typedef __attribute__((ext_vector_type(4))) float f32x4_t;     // MFMA C/D frag

// ---------------- workspace layout (BYTE offsets) ----------------
static const size_t OFF_STATS= 0;                  // fp32 [2 parity][64 b][8]: 4096
static const size_t OFF_COND = 4096;               // int[512]: 2048
static const size_t OFF_BAR  = 6144;               // int[320]: 1280
static const size_t OFF_H2B  = 7424;               // fp32 [256 ublk][64 b][4]: 262144
static const size_t OFF_HS   = 269568;             // f16 [2][3][256 ublk][64 b][4]: 786432
static const size_t OFF_YB   = 1056000;            // f16 y [64 fblk][64 b][4]: 32768
static const size_t OFF_PW0  = 1088768;            // f16 [256 g][40 kt][512]: 10485760
static const size_t OFF_PW1  = 11574528;           // f16 [256][64][512]: 16777216
static const size_t OFF_PW2  = 28351744;           // f16 [256][64][512]: 16777216
static const size_t ZERO_BYTES = OFF_PW0;          // state region zeroed each launch
// bar int-offsets: sub[i]=i*16 (i<8, monotonic, never reset); master=128;
// relay[i]=144+i*16.

__device__ __forceinline__ float sigm(float x) {
    return 1.0f / (1.0f + __expf(-x));
}

__device__ __forceinline__ ushort_t f2h(float x) {   // RNE fp32->fp16
    _Float16 h = (_Float16)x;
    union { _Float16 h; ushort_t u; } v; v.h = h;
    return v.u;
}
__device__ __forceinline__ float h2f(ushort_t u) {
    union { ushort_t u; _Float16 h; } v; v.u = u;
    return (float)v.h;
}

// ---- write-through (device-coherent) stores ----
__device__ __forceinline__ void store_uc_b64(void* p, unsigned long long v) {
    asm volatile("global_store_dwordx2 %0, %1, off sc0 sc1"
                 :: "v"(p), "v"(v) : "memory");
}
__device__ __forceinline__ void store_uc_b128(void* p, f32x4_t v) {
    asm volatile("global_store_dwordx4 %0, %1, off sc0 sc1"
                 :: "v"(p), "v"(v) : "memory");
}
__device__ __forceinline__ void drain_vmem() {
    asm volatile("s_waitcnt vmcnt(0)" ::: "memory");
}

// Hierarchical MONOTONIC barrier (R5): parallel sub-line arrival, no reset,
// no releaser drain, relaxed polls (agent-scope atomics read the coherence
// point), rare acquire backstop only.
__device__ __forceinline__ void phase_sync(int* bar, int epoch, int g) {
    drain_vmem();        // own write-through stores reach coherence point
    __syncthreads();
    if (threadIdx.x == 0) {
        const int sub = g & 7;
        const int prev = __hip_atomic_fetch_add(bar + sub * 16, 1,
                                                __ATOMIC_RELAXED, __HIP_MEMORY_SCOPE_AGENT);
        if (prev == epoch * 32 - 1) {
            const int pm = __hip_atomic_fetch_add(bar + 128, 1,
                                                  __ATOMIC_RELAXED, __HIP_MEMORY_SCOPE_AGENT);
            if (pm == epoch * 8 - 1) {
                #pragma unroll
                for (int i = 0; i < 8; ++i)
                    __hip_atomic_store(bar + 144 + i * 16, epoch, __ATOMIC_RELAXED,
                                       __HIP_MEMORY_SCOPE_AGENT);
            }
        }
        int* myrelay = bar + 144 + sub * 16;
        int spins = 0;
        while (__hip_atomic_load(myrelay, __ATOMIC_RELAXED,
                                 __HIP_MEMORY_SCOPE_AGENT) < epoch) {
            __builtin_amdgcn_s_sleep(1);
            if ((++spins & 255) == 0)
                (void)__hip_atomic_load(myrelay, __ATOMIC_ACQUIRE,
                                        __HIP_MEMORY_SCOPE_AGENT);
        }
    }
    __syncthreads();
}

// Prep: decode conditioned_lst (bool-u8 vs int32 sniff).
__global__ void prep_kernel(const unsigned char* __restrict__ condraw,
                            unsigned char* __restrict__ wsb) {
    __shared__ int s_not_int32;
    const int tid = threadIdx.x;
    if (tid == 0) s_not_int32 = 0;
    __syncthreads();
    if (tid < 512 && (tid & 3) != 0) {
        if (condraw[tid] != 0) s_not_int32 = 1;
    }
    __syncthreads();
    const int is32 = (s_not_int32 == 0);
    int* condw = (int*)(wsb + OFF_COND);
    if (tid < 512) {
        int cv = is32 ? ((const int*)condraw)[tid] : (int)condraw[tid];
        condw[tid] = (cv != 0) ? 1 : 0;
    }
}

// Repack fp32 weights -> fp16 in MFMA B-fragment order (unchanged).
__global__ void repack_kernel(const float* __restrict__ W0,
                              const float* __restrict__ W1,
                              const float* __restrict__ W2,
                              unsigned char* __restrict__ wsb) {
    ushort_t* P0 = (ushort_t*)(wsb + OFF_PW0);
    ushort_t* P1 = (ushort_t*)(wsb + OFF_PW1);
    ushort_t* P2 = (ushort_t*)(wsb + OFF_PW2);
    const size_t stride = (size_t)gridDim.x * blockDim.x;
    const size_t tid = (size_t)blockIdx.x * blockDim.x + threadIdx.x;
    const size_t N0 = (size_t)256 * 40 * 512;
    const size_t N12 = (size_t)256 * 64 * 512;
    for (size_t i = tid; i < N0; i += stride) {
        const int g = (int)(i / 20480);
        const int r = (int)(i % 20480);
        const int kt = r >> 9, s = r & 511, L = s >> 3, j = s & 7;
        const int k = kt * 32 + ((L >> 4) << 3) + j;
        const int n = L & 15;
        const int col = ((n >> 2) << 10) + (g << 2) + (n & 3);
        P0[i] = f2h(W0[(size_t)k * 4096 + col]);
    }
    for (size_t i = tid; i < N12; i += stride) {
        const int g = (int)(i / 32768);
        const int r = (int)(i % 32768);
        const int kt = r >> 9, s = r & 511, L = s >> 3, j = s & 7;
        const int k = kt * 32 + ((L >> 4) << 3) + j;
        const int n = L & 15;
        const int col = ((n >> 2) << 10) + (g << 2) + (n & 3);
        const size_t src = (size_t)k * 4096 + col;
        P1[i] = f2h(W1[src]);
        P2[i] = f2h(W2[src]);
    }
}

__global__ void __launch_bounds__(NTH, 2)
lstm_persistent(const float* __restrict__ input,
                const float* __restrict__ b0, const float* __restrict__ b1,
                const float* __restrict__ b2,
                const float* __restrict__ Wd, const float* __restrict__ bd,
                const float* __restrict__ gamma, const float* __restrict__ beta,
                float* __restrict__ out, unsigned char* __restrict__ wsb) {
    const int g = blockIdx.x;
    const int tid = threadIdx.x;
    const int lane = tid & 63;
    const int wv = __builtin_amdgcn_readfirstlane(tid >> 6);  // 0..7
    const int ln15 = lane & 15;
    const int quad = lane >> 4;

    float* h2b = (float*)(wsb + OFF_H2B);          // fp32 [256 ublk][64 b][4]
    float* stats = (float*)(wsb + OFF_STATS);      // fp32 [2][64][8]
    int* bar = (int*)(wsb + OFF_BAR);
    ushort_t* hs = (ushort_t*)(wsb + OFF_HS);      // f16 [2][3][256][64][4]
    ushort_t* yb = (ushort_t*)(wsb + OFF_YB);      // f16 y [64 fblk][64 b][4]
    const size_t HSZ = (size_t)256 * 64 * 4;       // ushorts per [parity][layer] tile

    __shared__ f16x8_t lds_pw0[40 * 64];     // 40 KB: L0 B-frags
    __shared__ f32x4_t lds_wd4[1024];        // 16 KB: Wd cols (g<64)
    __shared__ float zbuf[128 * WPAD];       // 34.8 KB
    __shared__ float zbuf2[128];             // per-batch (mu, rs)
    __shared__ float hbuf[64 * 5];           // 1.25 KB gate-stage (stride-5: 2-way free)
    __shared__ int lds_cond[512];            // 2 KB

    const int u0 = g << 2;
    const int f0 = g << 2;
    const int k0 = (wv << 5) + (quad << 3);  // this lane's x-feature base
    const int fb0 = k0 >> 2;

    // B-frags in regs: Bw[0..3] = x-part kts (4wv+c); Bw[4..7] = h-part
    // kts (32+4wv+c).
    f16x8_t Bw1[8], Bw2[8];
    {
        const ushort_t* p1 = (const ushort_t*)(wsb + OFF_PW1) +
                             (size_t)g * 64 * 512 + (size_t)lane * 8;
        const ushort_t* p2 = (const ushort_t*)(wsb + OFF_PW2) +
                             (size_t)g * 64 * 512 + (size_t)lane * 8;
        #pragma unroll
        for (int i = 0; i < 4; ++i) {
            Bw1[i]     = *(const f16x8_t*)(p1 + (size_t)((wv << 2) + i) * 512);
            Bw1[4 + i] = *(const f16x8_t*)(p1 + (size_t)(32 + (wv << 2) + i) * 512);
            Bw2[i]     = *(const f16x8_t*)(p2 + (size_t)((wv << 2) + i) * 512);
            Bw2[4 + i] = *(const f16x8_t*)(p2 + (size_t)(32 + (wv << 2) + i) * 512);
        }
    }
    {
        const f16x8_t* src = (const f16x8_t*)((const ushort_t*)(wsb + OFF_PW0) +
                                              (size_t)g * 40 * 512);
        for (int i = tid; i < 40 * 64; i += NTH) lds_pw0[i] = src[i];
    }
    if (g < 64) {
        for (int k = tid; k < 1024; k += NTH)
            lds_wd4[k] = *(const f32x4_t*)(Wd + (size_t)k * F + f0);
    }
    for (int i = tid; i < 512; i += NTH) lds_cond[i] = ((const int*)(wsb + OFF_COND))[i];

    // R4 gate map (zbuf reads stride-1, conflict-free): eb=tid&63, eu=tid>>6.
    // Global stores go through hbuf staging -> wave0/1 contiguous stores.
    const int ebo = tid & 63;
    const int euo = (tid >> 6) & 3;

    float bias0[4], bias1[4], bias2[4];
    if (tid < 256) {
        #pragma unroll
        for (int q = 0; q < 4; ++q) {
            bias0[q] = b0[(q << 10) + u0 + euo];
            bias1[q] = b1[(q << 10) + u0 + euo];
            bias2[q] = b2[(q << 10) + u0 + euo];
        }
    }
    // per-lane LN params for this lane's 8 x-features (survive inv in regs)
    float gmv[8], btv[8];
    {
        const float4 g0 = *(const float4*)(gamma + k0);
        const float4 g1 = *(const float4*)(gamma + k0 + 4);
        const float4 t0 = *(const float4*)(beta + k0);
        const float4 t1 = *(const float4*)(beta + k0 + 4);
        gmv[0]=g0.x; gmv[1]=g0.y; gmv[2]=g0.z; gmv[3]=g0.w;
        gmv[4]=g1.x; gmv[5]=g1.y; gmv[6]=g1.z; gmv[7]=g1.w;
        btv[0]=t0.x; btv[1]=t0.y; btv[2]=t0.z; btv[3]=t0.w;
        btv[4]=t1.x; btv[5]=t1.y; btv[6]=t1.z; btv[7]=t1.w;
    }
    float4 gm4 = {0,0,0,0}, bt4 = {0,0,0,0}, bd4 = {0,0,0,0};
    if (g < 64 && wv == 1) {       // out-writer wave's f-slice LN params
        gm4 = *(const float4*)(gamma + f0);
        bt4 = *(const float4*)(beta + f0);
    }
    if (g < 64 && wv == 0) {
        bd4 = *(const float4*)(bd + f0);
    }
    __syncthreads();

    float creg0 = 0.f, creg1 = 0.f, creg2 = 0.f;

    f32x4_t acc0[4], acc1[4], acc2[4];
    #pragma unroll
    for (int mt = 0; mt < 4; ++mt) {
        acc0[mt] = (f32x4_t){0.f, 0.f, 0.f, 0.f};
        acc1[mt] = (f32x4_t){0.f, 0.f, 0.f, 0.f};
        acc2[mt] = (f32x4_t){0.f, 0.f, 0.f, 0.f};
    }

    auto ld_frag = [&](const char* p) -> f16x8_t {
        union { unsigned long long q[2]; f16x8_t v; } u;
        u.q[0] = *(const unsigned long long*)(p);
        u.q[1] = *(const unsigned long long*)(p + 512);
        return u.v;
    };

    // single 4-kt slab (A cols (4wv+c)*32 of base)
    auto mm4 = [&](f32x4_t (&acc)[4], const ushort_t* base,
                   const f16x8_t (&Bw)[8], const int boff) {
        f16x8_t Ab[4][4];
        const char* bb = (const char*)base + (size_t)ln15 * 8 +
                         (size_t)(quad << 1) * 512;
        #pragma unroll
        for (int c = 0; c < 4; ++c) {
            const char* pc = bb + (size_t)((wv << 2) + c) * 4096;
            #pragma unroll
            for (int mt = 0; mt < 4; ++mt)
                Ab[c][mt] = ld_frag(pc + mt * 128);
        }
        #pragma unroll
        for (int c = 0; c < 4; ++c) {
            #pragma unroll
            for (int mt = 0; mt < 4; ++mt)
                acc[mt] = __builtin_amdgcn_mfma_f32_16x16x32_f16(
                    Ab[c][mt], Bw[boff + c], acc[mt], 0, 0, 0);
        }
    };

    // DUAL slab: x-part of layer (accX, BwX[0..3]) + h-part of prev layer
    // (accH, B-frags BH) share the SAME A fragments (cols (4wv+c)*32).
    // Loads A once, issues 8 MFMAs. BH from regs (Bw*[4..7]) or LDS (L0).
    auto mm4_dual_reg = [&](f32x4_t (&accX)[4], const f16x8_t (&BwX)[8],
                            f32x4_t (&accH)[4], const f16x8_t (&BwH)[8],
                            const ushort_t* base) {
        f16x8_t Ab[4][4];
        const char* bb = (const char*)base + (size_t)ln15 * 8 +
                         (size_t)(quad << 1) * 512;
        #pragma unroll
        for (int c = 0; c < 4; ++c) {
            const char* pc = bb + (size_t)((wv << 2) + c) * 4096;
            #pragma unroll
            for (int mt = 0; mt < 4; ++mt)
                Ab[c][mt] = ld_frag(pc + mt * 128);
        }
        #pragma unroll
        for (int c = 0; c < 4; ++c) {
            #pragma unroll
            for (int mt = 0; mt < 4; ++mt)
                accX[mt] = __builtin_amdgcn_mfma_f32_16x16x32_f16(
                    Ab[c][mt], BwX[c], accX[mt], 0, 0, 0);
            #pragma unroll
            for (int mt = 0; mt < 4; ++mt)
                accH[mt] = __builtin_amdgcn_mfma_f32_16x16x32_f16(
                    Ab[c][mt], BwH[4 + c], accH[mt], 0, 0, 0);
        }
    };
    auto mm4_dual_lds0 = [&](f32x4_t (&accX)[4], const f16x8_t (&BwX)[8],
                             f32x4_t (&accH)[4], const ushort_t* base) {
        f16x8_t Ab[4][4];
        const char* bb = (const char*)base + (size_t)ln15 * 8 +
                         (size_t)(quad << 1) * 512;
        #pragma unroll
        for (int c = 0; c < 4; ++c) {
            const char* pc = bb + (size_t)((wv << 2) + c) * 4096;
            #pragma unroll
            for (int mt = 0; mt < 4; ++mt)
                Ab[c][mt] = ld_frag(pc + mt * 128);
        }
        #pragma unroll
        for (int c = 0; c < 4; ++c) {
            const f16x8_t Bh = lds_pw0[(8 + (wv << 2) + c) * 64 + lane];
            #pragma unroll
            for (int mt = 0; mt < 4; ++mt)
                accX[mt] = __builtin_amdgcn_mfma_f32_16x16x32_f16(
                    Ab[c][mt], BwX[c], accX[mt], 0, 0, 0);
            #pragma unroll
            for (int mt = 0; mt < 4; ++mt)
                accH[mt] = __builtin_amdgcn_mfma_f32_16x16x32_f16(
                    Ab[c][mt], Bh, accH[mt], 0, 0, 0);
        }
    };

    // epilogue: zbuf reduce (conflict-free map) + gates -> hbuf stage ->
    // wave0: contiguous 512B f16 store; wave1: contiguous 1KB f32 store.
    auto epilogue = [&](f32x4_t (&acc)[4], const float (&bi)[4], float& cr,
                        ushort_t* hdst, float* h2dst) {
        __syncthreads();
        {
            float* zrow = zbuf + (size_t)(wv * 16 + ln15) * WPAD;
            #pragma unroll
            for (int mt = 0; mt < 4; ++mt)
                *(f32x4_t*)(zrow + mt * 16 + (quad << 2)) = acc[mt];
            #pragma unroll
            for (int mt = 0; mt < 4; ++mt) acc[mt] = (f32x4_t){0.f, 0.f, 0.f, 0.f};
        }
        __syncthreads();
        if (tid < 256) {   // gates: (b=ebo, unit u0+euo); zbuf reads stride-1
            float z[4];
            #pragma unroll
            for (int q = 0; q < 4; ++q) {
                float s = bi[q];
                #pragma unroll
                for (int w = 0; w < 8; ++w)
                    s += zbuf[(size_t)(w * 16 + q * 4 + euo) * WPAD + ebo];
                z[q] = s;
            }
            const float ig = sigm(z[0]);
            const float gg = tanhf(z[1]);
            const float fg = sigm(z[2] + 1.0f);   // forget_bias = 1.0
            const float og = sigm(z[3]);
            const float cn = cr * fg + ig * gg;
            const float hn = og * tanhf(cn);
            cr = cn;
            hbuf[ebo * 5 + euo] = hn;
        }
        __syncthreads();
        if (wv == 0) {     // f16 pack: [b=lane][u0..u0+3] -> 8B/lane, 512B total
            const float h0v = hbuf[lane * 5 + 0];
            const float h1v = hbuf[lane * 5 + 1];
            const float h2v = hbuf[lane * 5 + 2];
            const float h3v = hbuf[lane * 5 + 3];
            unsigned long long pk =
                (unsigned long long)f2h(h0v) |
                ((unsigned long long)f2h(h1v) << 16) |
                ((unsigned long long)f2h(h2v) << 32) |
                ((unsigned long long)f2h(h3v) << 48);
            store_uc_b64(hdst + (size_t)g * 256 + lane * 4, pk);
        } else if (wv == 1 && h2dst) {   // fp32: 16B/lane, 1KB total
            f32x4_t v;
            v[0] = hbuf[lane * 5 + 0];
            v[1] = hbuf[lane * 5 + 1];
            v[2] = hbuf[lane * 5 + 2];
            v[3] = hbuf[lane * 5 + 3];
            store_uc_b128(h2dst + (size_t)g * 256 + lane * 4, v);
        }
    };

    int epoch = 0;
    for (int t = 0; t < T; ++t) {
        const int p = t & 1;
        const int pn = p ^ 1;
        ushort_t* hs0n = hs + (size_t)(pn * 3 + 0) * HSZ;
        ushort_t* hs1n = hs + (size_t)(pn * 3 + 1) * HSZ;
        ushort_t* hs2n = hs + (size_t)(pn * 3 + 2) * HSZ;

        // THE one inv per step.
        __builtin_amdgcn_fence(__ATOMIC_ACQUIRE, "agent");

        // ================= phase 0 =================
        // early x loads (into f16-packed regs) -- overlap with stats RT
        const int condt = (t == 0) || (lds_cond[t] != 0);
        unsigned long long xr0[4], xr1[4];
        if (condt) {
            #pragma unroll
            for (int mt = 0; mt < 4; ++mt) {
                const int b = ln15 + (mt << 4);
                const float* ip = input + (size_t)b * (T * F) + (size_t)t * F + k0;
                const float4 a0 = *(const float4*)(ip);
                const float4 a1 = *(const float4*)(ip + 4);
                xr0[mt] = (unsigned long long)f2h(a0.x) |
                          ((unsigned long long)f2h(a0.y) << 16) |
                          ((unsigned long long)f2h(a0.z) << 32) |
                          ((unsigned long long)f2h(a0.w) << 48);
                xr1[mt] = (unsigned long long)f2h(a1.x) |
                          ((unsigned long long)f2h(a1.y) << 16) |
                          ((unsigned long long)f2h(a1.z) << 32) |
                          ((unsigned long long)f2h(a1.w) << 48);
            }
        } else {
            #pragma unroll
            for (int mt = 0; mt < 4; ++mt) {
                const int b = ln15 + (mt << 4);
                xr0[mt] = *(const unsigned long long*)(yb + ((size_t)fb0 * 64 + b) * 4);
                xr1[mt] = *(const unsigned long long*)(yb + ((size_t)(fb0 + 1) * 64 + b) * 4);
            }
        }
        // early emit load (dense wv1)
        unsigned long long yqe = 0;
        if (g < 64 && wv == 1 && t > 0)
            yqe = *(const unsigned long long*)(yb + ((size_t)g * 64 + lane) * 4);
        // stats of step t-1 (parity pn) -> mu/rs
        float2 svst = {0.f, 0.f};
        if (tid < 64)
            svst = *(const float2*)(stats + (size_t)pn * (64 * 8) + tid * 8);
        // dense blocks' deferred L2-h prefetch (reads parity-p h2 = h2(t-1))
        if (g < 64)
            mm4(acc2, hs + (size_t)(p * 3 + 2) * HSZ, Bw2, 4);
        if (tid < 64) {
            const float mu = svst.x * (1.0f / F);
            const float var = svst.y * (1.0f / F) - mu * mu;
            zbuf2[tid * 2] = mu;
            zbuf2[tid * 2 + 1] = rsqrtf(var + 1e-12f);
        }
        __syncthreads();
        // out-emit: dense wv1 writes step t-1's output for f-slice g
        if (g < 64 && wv == 1 && t > 0) {
            union { unsigned long long q; ushort_t s[4]; } yq; yq.q = yqe;
            const float mu = zbuf2[lane * 2], rs = zbuf2[lane * 2 + 1];
            float4 o;
            o.x = fmaxf((h2f(yq.s[0]) - mu) * rs * gm4.x + bt4.x, 0.0f);
            o.y = fmaxf((h2f(yq.s[1]) - mu) * rs * gm4.y + bt4.y, 0.0f);
            o.z = fmaxf((h2f(yq.s[2]) - mu) * rs * gm4.z + bt4.z, 0.0f);
            o.w = fmaxf((h2f(yq.s[3]) - mu) * rs * gm4.w + bt4.w, 0.0f);
            *(float4*)(out + (size_t)lane * (T * F) + (size_t)(t - 1) * F + f0) = o;
        }
        // x-construct: x = condt ? input : relu(LN(y_{t-1}))
        {
            f16x8_t Ax[4];
            #pragma unroll
            for (int mt = 0; mt < 4; ++mt) {
                union { unsigned long long q[2]; f16x8_t v;
                        ushort_t s[8]; } ux;
                if (condt) {
                    ux.q[0] = xr0[mt]; ux.q[1] = xr1[mt];
                } else {
                    const int b = ln15 + (mt << 4);
                    union { unsigned long long q; ushort_t s[4]; } y0, y1;
                    y0.q = xr0[mt]; y1.q = xr1[mt];
                    const float mu = zbuf2[b * 2], rs = zbuf2[b * 2 + 1];
                    #pragma unroll
                    for (int j = 0; j < 4; ++j) {
                        ux.s[j] = f2h(fmaxf((h2f(y0.s[j]) - mu) * rs * gmv[j] + btv[j], 0.0f));
                        ux.s[4 + j] = f2h(fmaxf((h2f(y1.s[j]) - mu) * rs * gmv[4 + j] + btv[4 + j], 0.0f));
                    }
                }
                Ax[mt] = ux.v;
            }
            const f16x8_t Bb = lds_pw0[wv * 64 + lane];
            #pragma unroll
            for (int mt = 0; mt < 4; ++mt)
                acc0[mt] = __builtin_amdgcn_mfma_f32_16x16x32_f16(
                    Ax[mt], Bb, acc0[mt], 0, 0, 0);
        }
        epilogue(acc0, bias0, creg0, hs0n, nullptr);
        phase_sync(bar, ++epoch, g);

        // ===== phase 1: L1-x + L0-h (shared A = h0_t), ALL blocks =====
        mm4_dual_lds0(acc1, Bw1, acc0, hs0n);
        epilogue(acc1, bias1, creg1, hs1n, nullptr);
        phase_sync(bar, ++epoch, g);

        // ===== phase 2: L2-x + L1-h (shared A = h1_t), ALL blocks =====
        mm4_dual_reg(acc2, Bw2, acc1, Bw1, hs1n);
        epilogue(acc2, bias2, creg2, hs2n, h2b);
        phase_sync(bar, ++epoch, g);

        // ===== phase 3: dense y + stats (g<64) / L2-h prefetch (g>=64) =====
        if (g < 64) {
            float accd[4] = {0.f, 0.f, 0.f, 0.f};
            #pragma unroll
            for (int half = 0; half < 2; ++half) {
                f32x4_t hv[16];
                const f32x4_t* hb4 = (const f32x4_t*)h2b +
                    (size_t)(wv * 32 + half * 16) * 64 + lane;
                #pragma unroll
                for (int i = 0; i < 16; ++i)
                    hv[i] = hb4[(size_t)i * 64];
                #pragma unroll
                for (int i = 0; i < 16; ++i) {
                    const int k = (wv << 7) + (half << 6) + (i << 2);
                    #pragma unroll
                    for (int j = 0; j < 4; ++j) {
                        const f32x4_t w4 = lds_wd4[k + j];
                        accd[0] = fmaf(w4[0], hv[i][j], accd[0]);
                        accd[1] = fmaf(w4[1], hv[i][j], accd[1]);
                        accd[2] = fmaf(w4[2], hv[i][j], accd[2]);
                        accd[3] = fmaf(w4[3], hv[i][j], accd[3]);
                    }
                }
            }
            __syncthreads();
            #pragma unroll
            for (int jj = 0; jj < 4; ++jj)
                zbuf[(size_t)(wv * 16 + jj) * WPAD + lane] = accd[jj];
            __syncthreads();
            if (wv == 0) {
                float yv[4];
                float s = 0.f, ss = 0.f;
                #pragma unroll
                for (int jj = 0; jj < 4; ++jj) {
                    float y = 0.f;
                    #pragma unroll
                    for (int w = 0; w < 8; ++w)
                        y += zbuf[(size_t)(w * 16 + jj) * WPAD + lane];
                    y += (jj == 0) ? bd4.x : (jj == 1) ? bd4.y : (jj == 2) ? bd4.z : bd4.w;
                    yv[jj] = y;
                    s += y;
                    ss += y * y;
                }
                unsigned long long pk =
                    (unsigned long long)f2h(yv[0]) |
                    ((unsigned long long)f2h(yv[1]) << 16) |
                    ((unsigned long long)f2h(yv[2]) << 32) |
                    ((unsigned long long)f2h(yv[3]) << 48);
                store_uc_b64(yb + ((size_t)g * 64 + lane) * 4, pk);
                float* st = stats + (size_t)p * (64 * 8);
                atomicAdd(&st[(size_t)lane * 8], s);
                atomicAdd(&st[(size_t)lane * 8 + 1], ss);
            }
        } else if (g == 64 && wv == 0) {
            float* st2 = stats + (size_t)pn * (64 * 8);
            store_uc_b64(&st2[(size_t)lane * 8], 0ULL);
        }
        if (g >= 64 && t + 1 < T)
            mm4(acc2, hs2n, Bw2, 4);     // L2-h prefetch (dense defers to next P0)
        phase_sync(bar, ++epoch, g);
    }

    // post-loop: emit step T-1's output (dense blocks only; block-local)
    if (g < 64) {
        __builtin_amdgcn_fence(__ATOMIC_ACQUIRE, "agent");
        if (tid < 64) {
            const float2 sv = *(const float2*)(stats + (size_t)((T - 1) & 1) * (64 * 8) + tid * 8);
            const float mu = sv.x * (1.0f / F);
            const float var = sv.y * (1.0f / F) - mu * mu;
            zbuf2[tid * 2] = mu;
            zbuf2[tid * 2 + 1] = rsqrtf(var + 1e-12f);
        }
        __syncthreads();
        if (wv == 1) {
            union { unsigned long long q; ushort_t s[4]; } yq;
            yq.q = *(const unsigned long long*)(yb + ((size_t)g * 64 + lane) * 4);
            const float mu = zbuf2[lane * 2], rs = zbuf2[lane * 2 + 1];
            float4 o;
            o.x = fmaxf((h2f(yq.s[0]) - mu) * rs * gm4.x + bt4.x, 0.0f);
            o.y = fmaxf((h2f(yq.s[1]) - mu) * rs * gm4.y + bt4.y, 0.0f);
            o.z = fmaxf((h2f(yq.s[2]) - mu) * rs * gm4.z + bt4.z, 0.0f);
            o.w = fmaxf((h2f(yq.s[3]) - mu) * rs * gm4.w + bt4.w, 0.0f);
            *(float4*)(out + (size_t)lane * (T * F) + (size_t)(T - 1) * F + f0) = o;
        }
    }
}

extern "C" void kernel_launch(void* const* d_in, const int* in_sizes, int n_in,
                              void* d_out, int out_size, void* d_ws, size_t ws_size,
                              hipStream_t stream) {
    const float* input = (const float*)d_in[0];
    const unsigned char* condraw = (const unsigned char*)d_in[1];
    const float* W0 = (const float*)d_in[2];
    const float* b0 = (const float*)d_in[3];
    const float* W1 = (const float*)d_in[4];
    const float* b1 = (const float*)d_in[5];
    const float* W2 = (const float*)d_in[6];
    const float* b2 = (const float*)d_in[7];
    const float* Wd = (const float*)d_in[8];
    const float* bd = (const float*)d_in[9];
    const float* gamma = (const float*)d_in[10];
    const float* beta = (const float*)d_in[11];
    float* out = (float*)d_out;
    unsigned char* wsb = (unsigned char*)d_ws;

    hipMemsetAsync(d_ws, 0, ZERO_BYTES, stream);
    prep_kernel<<<1, 512, 0, stream>>>(condraw, wsb);
    repack_kernel<<<2048, 256, 0, stream>>>(W0, W1, W2, wsb);
    lstm_persistent<<<NBLK, NTH, 0, stream>>>(input, b0, b1, b2, Wd, bd,
                                              gamma, beta, out, wsb);
}